// Round 9
// baseline (135.279 us; speedup 1.0000x reference)
//
#include <hip/hip_runtime.h>
#include <math.h>

typedef __bf16 bf16x8 __attribute__((ext_vector_type(8)));
typedef float  f32x4  __attribute__((ext_vector_type(4)));
typedef float  f32x16 __attribute__((ext_vector_type(16)));
typedef unsigned short u16x8 __attribute__((ext_vector_type(8)));

#define D_MODEL 1024
#define QDIM    64
#define HEADS   16
#define BATCH   2
#define SEQ     2048
#define M_ROWS  (BATCH*SEQ)        /* 4096 */
#define NCAT    (HEADS*3*QDIM)     /* 3072 */

__device__ __forceinline__ unsigned short f2bf(float f) {
    unsigned int u = __float_as_uint(f);
    u += 0x7fffu + ((u >> 16) & 1u);
    return (unsigned short)(u >> 16);
}

// async global->LDS, 16B per lane. LDS dest = wave-uniform base + lane*16.
__device__ __forceinline__ void gl16(const unsigned short* g, unsigned short* l) {
    __builtin_amdgcn_global_load_lds(
        (const __attribute__((address_space(1))) unsigned int*)g,
        (__attribute__((address_space(3))) unsigned int*)l, 16, 0, 0);
}

// ---------------- cast xi f32 -> bf16 ----------------
__global__ __launch_bounds__(256) void k_cvt_bf16(const float* __restrict__ in,
                                                  unsigned short* __restrict__ out) {
    int i = (blockIdx.x * 256 + threadIdx.x) * 8;
    f32x4 a = *(const f32x4*)(in + i);
    f32x4 b = *(const f32x4*)(in + i + 4);
    u16x8 o;
    o[0]=f2bf(a[0]); o[1]=f2bf(a[1]); o[2]=f2bf(a[2]); o[3]=f2bf(a[3]);
    o[4]=f2bf(b[0]); o[5]=f2bf(b[1]); o[6]=f2bf(b[2]); o[7]=f2bf(b[3]);
    *(u16x8*)(out + i) = o;
}

// ------- WcatT[3072][1024] bf16 + bcat[3072]; coalesced via LDS transpose -------
// Q weights pre-scaled by log2(e)/sqrt(SEQ) so attn can use exp2 directly.
__global__ __launch_bounds__(256) void k_prep_wcat(const float* __restrict__ Wq,
                                                   const float* __restrict__ Wk,
                                                   const float* __restrict__ Wv,
                                                   const float* __restrict__ bq,
                                                   const float* __restrict__ bk,
                                                   const float* __restrict__ bv,
                                                   unsigned short* __restrict__ WcatT,
                                                   float* __restrict__ bcat,
                                                   float qscale) {
    int blk = blockIdx.x;
    int dt = blk & 15, h = (blk >> 4) & 15, s = blk >> 8;
    const float* W = (s == 0) ? Wq : (s == 1) ? Wk : Wv;
    float sc = (s == 0) ? qscale : 1.0f;
    __shared__ float t[64][65];
    int tid = threadIdx.x;
    int dr = tid >> 2, qc = (tid & 3) * 16;
    const float* src = W + (size_t)h * (D_MODEL * QDIM) + (size_t)(dt * 64 + dr) * QDIM + qc;
#pragma unroll
    for (int j = 0; j < 4; ++j) {
        f32x4 v = *(const f32x4*)(src + j * 4);
        t[dr][qc + j * 4 + 0] = v[0]; t[dr][qc + j * 4 + 1] = v[1];
        t[dr][qc + j * 4 + 2] = v[2]; t[dr][qc + j * 4 + 3] = v[3];
    }
    __syncthreads();
    int q = tid >> 2, dc = (tid & 3) * 16;
    unsigned short* dst = WcatT + (size_t)(h * 192 + s * 64 + q) * D_MODEL + dt * 64 + dc;
#pragma unroll
    for (int j = 0; j < 2; ++j) {
        u16x8 o;
#pragma unroll
        for (int e = 0; e < 8; ++e) o[e] = f2bf(t[dc + j * 8 + e][q] * sc);
        *(u16x8*)(dst + j * 8) = o;
    }
    if (dt == 0 && tid < 64) {
        const float* bb = (s == 0) ? bq : (s == 1) ? bk : bv;
        bcat[h * 192 + s * 64 + tid] = bb[h * QDIM + tid] * sc;
    }
}

// ------- WoT[1024][1024] = Wo^T, coalesced via LDS transpose (256 blocks) -------
__global__ __launch_bounds__(256) void k_prep_wo(const float* __restrict__ Wo,
                                                 unsigned short* __restrict__ WoT) {
    int blk = blockIdx.x;
    int ct = blk & 15, rt = blk >> 4;
    __shared__ float t[64][65];
    int tid = threadIdx.x;
    int dr = tid >> 2, qc = (tid & 3) * 16;
    const float* src = Wo + (size_t)(rt * 64 + dr) * D_MODEL + ct * 64 + qc;
#pragma unroll
    for (int j = 0; j < 4; ++j) {
        f32x4 v = *(const f32x4*)(src + j * 4);
        t[dr][qc + j * 4 + 0] = v[0]; t[dr][qc + j * 4 + 1] = v[1];
        t[dr][qc + j * 4 + 2] = v[2]; t[dr][qc + j * 4 + 3] = v[3];
    }
    __syncthreads();
    int q = tid >> 2, dc = (tid & 3) * 16;
    unsigned short* dst = WoT + (size_t)(ct * 64 + q) * D_MODEL + rt * 64 + dc;
#pragma unroll
    for (int j = 0; j < 2; ++j) {
        u16x8 o;
#pragma unroll
        for (int e = 0; e < 8; ++e) o[e] = f2bf(t[dc + j * 8 + e][q]);
        *(u16x8*)(dst + j * 8) = o;
    }
}

// ---------------- tiled MFMA GEMM, global_load_lds staging (m97 structure) ----------------
template<bool OUT_BF16>
__global__ __launch_bounds__(256) void k_gemm(const unsigned short* __restrict__ A,
                                              const unsigned short* __restrict__ BT,
                                              const float* __restrict__ bias,
                                              void* __restrict__ Cout,
                                              int N, int Kd) {
    __shared__ __align__(16) unsigned short Alds[128 * 64];
    __shared__ __align__(16) unsigned short Blds[128 * 64];
    const int tid = threadIdx.x;
    const int lane = tid & 63, w = tid >> 6;
    const int g = lane >> 4, c = lane & 15;
    int nwg = gridDim.x * gridDim.y;
    int bid = blockIdx.y * gridDim.x + blockIdx.x;
    int sw = (bid & 7) * (nwg >> 3) + (bid >> 3);
    int bx = sw % gridDim.x, by = sw / gridDim.x;
    const int m0 = by * 128, n0 = bx * 128;
    const int wm = (w >> 1) * 64, wn = (w & 1) * 64;
    const int r8 = lane >> 3, chx = (lane & 7) ^ r8;
    const int swz = c & 7;
    f32x4 acc[4][4] = {};

    for (int k0 = 0; k0 < Kd; k0 += 64) {
        __builtin_amdgcn_sched_barrier(0);
        __builtin_amdgcn_s_barrier();
#pragma unroll
        for (int i = 0; i < 4; ++i) {
            int row = w * 32 + i * 8 + r8;
            gl16(A + (size_t)(m0 + row) * Kd + k0 + chx * 8, Alds + w * 2048 + i * 512);
            gl16(BT + (size_t)(n0 + row) * Kd + k0 + chx * 8, Blds + w * 2048 + i * 512);
        }
        asm volatile("s_waitcnt vmcnt(0)" ::: "memory");
        __builtin_amdgcn_s_barrier();
        __builtin_amdgcn_sched_barrier(0);
#pragma unroll
        for (int kk = 0; kk < 2; ++kk) {
            bf16x8 af[4], bfr[4];
#pragma unroll
            for (int mf = 0; mf < 4; ++mf) {
                int row = wm + mf * 16 + c;
                af[mf] = *(const bf16x8*)(Alds + row * 64 + (((kk * 4 + g) ^ swz) * 8));
            }
#pragma unroll
            for (int nf = 0; nf < 4; ++nf) {
                int row = wn + nf * 16 + c;
                bfr[nf] = *(const bf16x8*)(Blds + row * 64 + (((kk * 4 + g) ^ swz) * 8));
            }
            __builtin_amdgcn_s_setprio(1);
#pragma unroll
            for (int mf = 0; mf < 4; ++mf)
#pragma unroll
                for (int nf = 0; nf < 4; ++nf)
                    acc[mf][nf] = __builtin_amdgcn_mfma_f32_16x16x32_bf16(af[mf], bfr[nf], acc[mf][nf], 0, 0, 0);
            __builtin_amdgcn_s_setprio(0);
        }
    }

#pragma unroll
    for (int mf = 0; mf < 4; ++mf)
#pragma unroll
        for (int nf = 0; nf < 4; ++nf) {
            int col = n0 + wn + nf * 16 + c;
            float bb = bias[col];
#pragma unroll
            for (int r = 0; r < 4; ++r) {
                int row = m0 + wm + mf * 16 + 4 * g + r;
                float v = acc[mf][nf][r] + bb;
                if (OUT_BF16)
                    ((unsigned short*)Cout)[(size_t)row * N + col] = f2bf(v);
                else
                    ((float*)Cout)[(size_t)row * N + col] = v;
            }
        }
}

// ---------------- repack K,V into MFMA-fragment order (producer-side gather) ----------------
// grid: b*512 + h*32 + tile (1024 blocks). Per (b,h,tile): 8 K-frags + 8 V-frags,
// each 1KB, contiguous, so k_attn's gl16 sources are base + lane*16.
//  K frag f: lane(l31,hi) -> K[tile*64 + (f>>2)*32 + l31][(f&3)*16 + hi*8 ..+8)
//  V frag f: lane(l31,hi) -> VT[(f&1)*32 + l31][tile*64 + (f>>2)*32 + ((f>>1)&1)*16 + hi*8 ..+8)
__global__ __launch_bounds__(256) void k_repack(const unsigned short* __restrict__ qkv,
                                                unsigned short* __restrict__ kfrag,
                                                unsigned short* __restrict__ vfrag) {
    int blk = blockIdx.x;
    int kt = blk & 31, h = (blk >> 5) & 15, b = blk >> 9;
    __shared__ unsigned short ktile[64][72];
    __shared__ unsigned short vtile[64][72];
    int tid = threadIdx.x;
#pragma unroll
    for (int j = 0; j < 2; ++j) {
        int cid = tid + j * 256;
        int row = cid >> 3, ch = (cid & 7) * 8;
        const unsigned short* base = qkv + (size_t)(b * SEQ + kt * 64 + row) * NCAT + h * 192;
        *(u16x8*)&ktile[row][ch] = *(const u16x8*)(base + 64 + ch);
        *(u16x8*)&vtile[row][ch] = *(const u16x8*)(base + 128 + ch);
    }
    __syncthreads();
    size_t obase = (size_t)blk * 4096;    // 4096 shorts = 8KB per (b,h,tile)
#pragma unroll
    for (int j = 0; j < 2; ++j) {
        int p = tid + j * 256;            // (frag,lane) pair: f = p>>6, lane = p&63
        int f = p >> 6, l31 = p & 31, hi = (p >> 5) & 1;
        *(u16x8*)(kfrag + obase + p * 8) =
            *(const u16x8*)&ktile[(f >> 2) * 32 + l31][(f & 3) * 16 + hi * 8];
        int vv = (f & 1) * 32 + l31;
        int k0 = (f >> 2) * 32 + ((f >> 1) & 1) * 16 + hi * 8;
        u16x8 o;
#pragma unroll
        for (int e = 0; e < 8; ++e) o[e] = vtile[k0 + e][vv];
        *(u16x8*)(vfrag + obase + p * 8) = o;
    }
}

// ---------------- flash attention: split-K, 32x32 MFMA, fragment LDS ----------------
// grid 2048: blk = (bid&7)*256 + (bid>>3); ks = blk&1 (key-range half),
// rest = blk>>1 -> (qt,h,b). Each block: 16 kv-tiles, writes f32 partial
// O[64][64] + rowsum[64] to workspace (deferred denominator -> mergeable).
__global__ __launch_bounds__(256) void k_attn(const unsigned short* __restrict__ qkv,
                                              const unsigned short* __restrict__ kfrag,
                                              const unsigned short* __restrict__ vfrag,
                                              float* __restrict__ po,
                                              float* __restrict__ rs) {
    int bid = blockIdx.x;
    int blk = (bid & 7) * 256 + (bid >> 3);   // XCD-chunked
    int ks = blk & 1, rest = blk >> 1;
    int qt = rest & 31, h = (rest >> 5) & 15, b = rest >> 9;
    int tid = threadIdx.x, w = tid >> 6, lane = tid & 63;
    int l31 = lane & 31, hi = lane >> 5;
    int qh = w & 1, kh = w >> 1;

    __shared__ __align__(16) unsigned char KV[2][16384];  // per buf: K frags 8KB | V frags 8KB

    const int qbase = b * SEQ + qt * 64;
    const unsigned short* qrow = qkv + (size_t)(qbase + qh * 32 + l31) * NCAT + h * 192;
    bf16x8 qf[4];
#pragma unroll
    for (int s = 0; s < 4; ++s) qf[s] = *(const bf16x8*)(qrow + s * 16 + hi * 8);

    f32x16 o0 = {}, o1 = {};
    float rsum = 0.f;

    // fragment streams for this (b,h), starting at tile ks*16
    const size_t fb = ((size_t)(b * 512 + h * 32) + ks * 16) * 4096;
    const unsigned short* ks0 = kfrag + fb + (w)     * 512 + lane * 8;
    const unsigned short* ks1 = kfrag + fb + (w + 4) * 512 + lane * 8;
    const unsigned short* vs0 = vfrag + fb + (w)     * 512 + lane * 8;
    const unsigned short* vs1 = vfrag + fb + (w + 4) * 512 + lane * 8;
    const unsigned kd0 = w * 1024, kd1 = (w + 4) * 1024;
    const unsigned vd0 = 8192 + w * 1024, vd1 = 8192 + (w + 4) * 1024;
    const int lx = lane * 16;

    // prologue: stage tile 0 into buf 0
    gl16(ks0, (unsigned short*)&KV[0][kd0]);
    gl16(vs0, (unsigned short*)&KV[0][vd0]);
    gl16(ks1, (unsigned short*)&KV[0][kd1]);
    gl16(vs1, (unsigned short*)&KV[0][vd1]);
    ks0 += 4096; ks1 += 4096; vs0 += 4096; vs1 += 4096;
    asm volatile("s_waitcnt vmcnt(0)" ::: "memory");
    __builtin_amdgcn_s_barrier();

    const int NT = 16;   // split-K: half the key range
    for (int t = 0; t < NT; ++t) {
        const int cur = t & 1;
        if (t + 1 < NT) {
            gl16(ks0, (unsigned short*)&KV[cur ^ 1][kd0]);
            gl16(vs0, (unsigned short*)&KV[cur ^ 1][vd0]);
            gl16(ks1, (unsigned short*)&KV[cur ^ 1][kd1]);
            gl16(vs1, (unsigned short*)&KV[cur ^ 1][vd1]);
            ks0 += 4096; ks1 += 4096; vs0 += 4096; vs1 += 4096;
            asm volatile("s_waitcnt vmcnt(4)" ::: "memory");
        } else {
            asm volatile("s_waitcnt vmcnt(0)" ::: "memory");
        }
        __builtin_amdgcn_s_barrier();
        __builtin_amdgcn_sched_barrier(0);

        const unsigned char* Kf = &KV[cur][0];
        const unsigned char* Vf = &KV[cur][8192];

        // ---- S^T[32k][32q] = K . Q^T  (wave's k-half) ----
        f32x16 st = {};
        __builtin_amdgcn_s_setprio(1);
#pragma unroll
        for (int s = 0; s < 4; ++s) {
            bf16x8 kf = *(const bf16x8*)(Kf + (kh * 4 + s) * 1024 + lx);
            st = __builtin_amdgcn_mfma_f32_32x32x16_bf16(kf, qf[s], st, 0, 0, 0);
        }
        __builtin_amdgcn_s_setprio(0);

        // ---- P = exp2(S) (log2e pre-folded); lane-local rowsum; pack in-register ----
#pragma unroll
        for (int r = 0; r < 16; ++r) {
            float p = __builtin_amdgcn_exp2f(st[r]);
            st[r] = p;
            rsum += p;
        }
        unsigned int d0, d1, d2, d3, d4, d5, d6, d7;
        asm("v_cvt_pk_bf16_f32 %0, %1, %2" : "=v"(d0) : "v"(st[0]),  "v"(st[1]));
        asm("v_cvt_pk_bf16_f32 %0, %1, %2" : "=v"(d1) : "v"(st[2]),  "v"(st[3]));
        asm("v_cvt_pk_bf16_f32 %0, %1, %2" : "=v"(d2) : "v"(st[4]),  "v"(st[5]));
        asm("v_cvt_pk_bf16_f32 %0, %1, %2" : "=v"(d3) : "v"(st[6]),  "v"(st[7]));
        asm("v_cvt_pk_bf16_f32 %0, %1, %2" : "=v"(d4) : "v"(st[8]),  "v"(st[9]));
        asm("v_cvt_pk_bf16_f32 %0, %1, %2" : "=v"(d5) : "v"(st[10]), "v"(st[11]));
        asm("v_cvt_pk_bf16_f32 %0, %1, %2" : "=v"(d6) : "v"(st[12]), "v"(st[13]));
        asm("v_cvt_pk_bf16_f32 %0, %1, %2" : "=v"(d7) : "v"(st[14]), "v"(st[15]));
        // new_a = {a_lo, b_lo}; new_b = {a_hi, b_hi}
        asm("v_permlane32_swap_b32 %0, %1" : "+v"(d0), "+v"(d2));
        asm("v_permlane32_swap_b32 %0, %1" : "+v"(d1), "+v"(d3));
        asm("v_permlane32_swap_b32 %0, %1" : "+v"(d4), "+v"(d6));
        asm("v_permlane32_swap_b32 %0, %1" : "+v"(d5), "+v"(d7));
        union { unsigned int u[4]; bf16x8 v; } pa0, pa1;
        pa0.u[0] = d0; pa0.u[1] = d1; pa0.u[2] = d2; pa0.u[3] = d3;
        pa1.u[0] = d4; pa1.u[1] = d5; pa1.u[2] = d6; pa1.u[3] = d7;

        // ---- O[32q][64v] += P . V  (2 k-steps x 2 v-halves) ----
        __builtin_amdgcn_s_setprio(1);
        {
            bf16x8 vf00 = *(const bf16x8*)(Vf + (kh * 4 + 0) * 1024 + lx);
            bf16x8 vf01 = *(const bf16x8*)(Vf + (kh * 4 + 1) * 1024 + lx);
            bf16x8 vf10 = *(const bf16x8*)(Vf + (kh * 4 + 2) * 1024 + lx);
            bf16x8 vf11 = *(const bf16x8*)(Vf + (kh * 4 + 3) * 1024 + lx);
            o0 = __builtin_amdgcn_mfma_f32_32x32x16_bf16(pa0.v, vf00, o0, 0, 0, 0);
            o1 = __builtin_amdgcn_mfma_f32_32x32x16_bf16(pa0.v, vf01, o1, 0, 0, 0);
            o0 = __builtin_amdgcn_mfma_f32_32x32x16_bf16(pa1.v, vf10, o0, 0, 0, 0);
            o1 = __builtin_amdgcn_mfma_f32_32x32x16_bf16(pa1.v, vf11, o1, 0, 0, 0);
        }
        __builtin_amdgcn_s_setprio(0);
        __builtin_amdgcn_sched_barrier(0);
        __builtin_amdgcn_s_barrier();
    }

    // ---- merge kh partials within block; write split-K partials (f32) ----
    rsum += __shfl_xor(rsum, 32);
    __syncthreads();
    float* red = (float*)&KV[0][0];          // [2 qh][32 q][64 v] f32 = 16 KB
    float* rsb = (float*)&KV[1][0];          // [2 kh][2 qh][32 q] f32
    if (kh == 1) {
#pragma unroll
        for (int r = 0; r < 16; ++r) {
            int q = (r & 3) + 8 * (r >> 2) + 4 * hi;
            red[(qh * 32 + q) * 64 + l31]      = o0[r];
            red[(qh * 32 + q) * 64 + 32 + l31] = o1[r];
        }
    }
    if (lane < 32) rsb[(kh * 2 + qh) * 32 + l31] = rsum;
    __syncthreads();
    float* pdst = po + (size_t)blk * 4096;
    if (kh == 0) {
#pragma unroll
        for (int r = 0; r < 16; ++r) {
            int q = (r & 3) + 8 * (r >> 2) + 4 * hi;
            pdst[(qh * 32 + q) * 64 + l31]      = o0[r] + red[(qh * 32 + q) * 64 + l31];
            pdst[(qh * 32 + q) * 64 + 32 + l31] = o1[r] + red[(qh * 32 + q) * 64 + 32 + l31];
        }
    }
    if (tid < 64) {
        int qq = tid & 31, qhh = tid >> 5;
        rs[(size_t)blk * 64 + tid] = rsb[qhh * 32 + qq] + rsb[(2 + qhh) * 32 + qq];
    }
}

// ---------------- combine split-K partials, normalize, emit bf16 attnb ----------------
// grid 1024 = rest (b,h,qt); partials at blk = rest*2 + ks.
__global__ __launch_bounds__(256) void k_reduce(const float* __restrict__ po,
                                                const float* __restrict__ rs,
                                                unsigned short* __restrict__ attn) {
    int rest = blockIdx.x;
    int qt = rest & 31, h = (rest >> 5) & 15, b = rest >> 9;
    int tid = threadIdx.x;
    int q = tid >> 2, vs = (tid & 3) * 16;
    const float* p0 = po + ((size_t)rest * 2 + 0) * 4096 + q * 64 + vs;
    const float* p1 = po + ((size_t)rest * 2 + 1) * 4096 + q * 64 + vs;
    float inv = 1.0f / (rs[((size_t)rest * 2) * 64 + q] + rs[((size_t)rest * 2 + 1) * 64 + q]);
    int row = b * SEQ + qt * 64 + q;
    unsigned short* dst = attn + (size_t)row * (HEADS * QDIM) + h * 64 + vs;
#pragma unroll
    for (int j = 0; j < 2; ++j) {
        f32x4 a0 = *(const f32x4*)(p0 + j * 8);
        f32x4 a1 = *(const f32x4*)(p0 + j * 8 + 4);
        f32x4 b0 = *(const f32x4*)(p1 + j * 8);
        f32x4 b1 = *(const f32x4*)(p1 + j * 8 + 4);
        u16x8 o;
        o[0] = f2bf((a0[0] + b0[0]) * inv); o[1] = f2bf((a0[1] + b0[1]) * inv);
        o[2] = f2bf((a0[2] + b0[2]) * inv); o[3] = f2bf((a0[3] + b0[3]) * inv);
        o[4] = f2bf((a1[0] + b1[0]) * inv); o[5] = f2bf((a1[1] + b1[1]) * inv);
        o[6] = f2bf((a1[2] + b1[2]) * inv); o[7] = f2bf((a1[3] + b1[3]) * inv);
        *(u16x8*)(dst + j * 8) = o;
    }
}

extern "C" void kernel_launch(void* const* d_in, const int* in_sizes, int n_in,
                              void* d_out, int out_size, void* d_ws, size_t ws_size,
                              hipStream_t stream) {
    const float* xi = (const float*)d_in[0];
    const float* Wq = (const float*)d_in[1];
    const float* bq = (const float*)d_in[2];
    const float* Wk = (const float*)d_in[3];
    const float* bk = (const float*)d_in[4];
    const float* Wv = (const float*)d_in[5];
    const float* bv = (const float*)d_in[6];
    const float* Wo = (const float*)d_in[7];
    const float* bo = (const float*)d_in[8];

    unsigned short* xi_bf = (unsigned short*)d_ws;
    unsigned short* WcatT = xi_bf + (size_t)M_ROWS * D_MODEL;
    unsigned short* WoT   = WcatT + (size_t)NCAT * D_MODEL;
    float*          bcat  = (float*)(WoT + (size_t)D_MODEL * D_MODEL);
    unsigned short* qkvc  = (unsigned short*)(bcat + NCAT);
    unsigned short* kfrag = qkvc + (size_t)M_ROWS * NCAT;
    unsigned short* vfrag = kfrag + (size_t)BATCH * HEADS * 32 * 4096;
    unsigned short* attnb = vfrag + (size_t)BATCH * HEADS * 32 * 4096;
    float*          po    = (float*)(attnb + (size_t)M_ROWS * (HEADS * QDIM));
    float*          rsbuf = po + (size_t)2048 * 4096;

    // fold softmax scale AND log2(e) into Q projection (attn uses exp2)
    float qscale = 1.4426950408889634f / sqrtf((float)SEQ);

    k_cvt_bf16<<<(M_ROWS * D_MODEL) / 2048, 256, 0, stream>>>(xi, xi_bf);
    k_prep_wcat<<<768, 256, 0, stream>>>(Wq, Wk, Wv, bq, bk, bv, WcatT, bcat, qscale);
    k_prep_wo<<<256, 256, 0, stream>>>(Wo, WoT);

    k_gemm<true><<<dim3(NCAT / 128, M_ROWS / 128), 256, 0, stream>>>(
        xi_bf, WcatT, bcat, (void*)qkvc, NCAT, D_MODEL);

    k_repack<<<BATCH * HEADS * (SEQ / 64), 256, 0, stream>>>(qkvc, kfrag, vfrag);

    k_attn<<<2 * BATCH * HEADS * (SEQ / 64), 256, 0, stream>>>(qkvc, kfrag, vfrag, po, rsbuf);

    k_reduce<<<BATCH * HEADS * (SEQ / 64), 256, 0, stream>>>(po, rsbuf, attnb);

    k_gemm<false><<<dim3(D_MODEL / 128, M_ROWS / 128), 256, 0, stream>>>(
        attnb, WoT, bo, d_out, D_MODEL, D_MODEL);
}

// Round 10
// 127.057 us; speedup vs baseline: 1.0647x; 1.0647x over previous
//
#include <hip/hip_runtime.h>
#include <math.h>

typedef __bf16 bf16x8 __attribute__((ext_vector_type(8)));
typedef float  f32x4  __attribute__((ext_vector_type(4)));
typedef float  f32x16 __attribute__((ext_vector_type(16)));
typedef unsigned short u16x8 __attribute__((ext_vector_type(8)));

#define D_MODEL 1024
#define QDIM    64
#define HEADS   16
#define BATCH   2
#define SEQ     2048
#define M_ROWS  (BATCH*SEQ)        /* 4096 */
#define NCAT    (HEADS*3*QDIM)     /* 3072 */

__device__ __forceinline__ unsigned short f2bf(float f) {
    unsigned int u = __float_as_uint(f);
    u += 0x7fffu + ((u >> 16) & 1u);
    return (unsigned short)(u >> 16);
}

// async global->LDS, 16B per lane. LDS dest = wave-uniform base + lane*16.
__device__ __forceinline__ void gl16(const unsigned short* g, unsigned short* l) {
    __builtin_amdgcn_global_load_lds(
        (const __attribute__((address_space(1))) unsigned int*)g,
        (__attribute__((address_space(3))) unsigned int*)l, 16, 0, 0);
}

// ---------------- cast xi f32 -> bf16 ----------------
__global__ __launch_bounds__(256) void k_cvt_bf16(const float* __restrict__ in,
                                                  unsigned short* __restrict__ out) {
    int i = (blockIdx.x * 256 + threadIdx.x) * 8;
    f32x4 a = *(const f32x4*)(in + i);
    f32x4 b = *(const f32x4*)(in + i + 4);
    u16x8 o;
    o[0]=f2bf(a[0]); o[1]=f2bf(a[1]); o[2]=f2bf(a[2]); o[3]=f2bf(a[3]);
    o[4]=f2bf(b[0]); o[5]=f2bf(b[1]); o[6]=f2bf(b[2]); o[7]=f2bf(b[3]);
    *(u16x8*)(out + i) = o;
}

// ------- WcatT[3072][1024] bf16 + bcat[3072]; coalesced via LDS transpose -------
// Q weights pre-scaled by log2(e)/sqrt(SEQ) so attn can use exp2 directly.
__global__ __launch_bounds__(256) void k_prep_wcat(const float* __restrict__ Wq,
                                                   const float* __restrict__ Wk,
                                                   const float* __restrict__ Wv,
                                                   const float* __restrict__ bq,
                                                   const float* __restrict__ bk,
                                                   const float* __restrict__ bv,
                                                   unsigned short* __restrict__ WcatT,
                                                   float* __restrict__ bcat,
                                                   float qscale) {
    int blk = blockIdx.x;
    int dt = blk & 15, h = (blk >> 4) & 15, s = blk >> 8;
    const float* W = (s == 0) ? Wq : (s == 1) ? Wk : Wv;
    float sc = (s == 0) ? qscale : 1.0f;
    __shared__ float t[64][65];
    int tid = threadIdx.x;
    int dr = tid >> 2, qc = (tid & 3) * 16;
    const float* src = W + (size_t)h * (D_MODEL * QDIM) + (size_t)(dt * 64 + dr) * QDIM + qc;
#pragma unroll
    for (int j = 0; j < 4; ++j) {
        f32x4 v = *(const f32x4*)(src + j * 4);
        t[dr][qc + j * 4 + 0] = v[0]; t[dr][qc + j * 4 + 1] = v[1];
        t[dr][qc + j * 4 + 2] = v[2]; t[dr][qc + j * 4 + 3] = v[3];
    }
    __syncthreads();
    int q = tid >> 2, dc = (tid & 3) * 16;
    unsigned short* dst = WcatT + (size_t)(h * 192 + s * 64 + q) * D_MODEL + dt * 64 + dc;
#pragma unroll
    for (int j = 0; j < 2; ++j) {
        u16x8 o;
#pragma unroll
        for (int e = 0; e < 8; ++e) o[e] = f2bf(t[dc + j * 8 + e][q] * sc);
        *(u16x8*)(dst + j * 8) = o;
    }
    if (dt == 0 && tid < 64) {
        const float* bb = (s == 0) ? bq : (s == 1) ? bk : bv;
        bcat[h * 192 + s * 64 + tid] = bb[h * QDIM + tid] * sc;
    }
}

// ------- WoT[1024][1024] = Wo^T, coalesced via LDS transpose (256 blocks) -------
__global__ __launch_bounds__(256) void k_prep_wo(const float* __restrict__ Wo,
                                                 unsigned short* __restrict__ WoT) {
    int blk = blockIdx.x;
    int ct = blk & 15, rt = blk >> 4;
    __shared__ float t[64][65];
    int tid = threadIdx.x;
    int dr = tid >> 2, qc = (tid & 3) * 16;
    const float* src = Wo + (size_t)(rt * 64 + dr) * D_MODEL + ct * 64 + qc;
#pragma unroll
    for (int j = 0; j < 4; ++j) {
        f32x4 v = *(const f32x4*)(src + j * 4);
        t[dr][qc + j * 4 + 0] = v[0]; t[dr][qc + j * 4 + 1] = v[1];
        t[dr][qc + j * 4 + 2] = v[2]; t[dr][qc + j * 4 + 3] = v[3];
    }
    __syncthreads();
    int q = tid >> 2, dc = (tid & 3) * 16;
    unsigned short* dst = WoT + (size_t)(ct * 64 + q) * D_MODEL + rt * 64 + dc;
#pragma unroll
    for (int j = 0; j < 2; ++j) {
        u16x8 o;
#pragma unroll
        for (int e = 0; e < 8; ++e) o[e] = f2bf(t[dc + j * 8 + e][q]);
        *(u16x8*)(dst + j * 8) = o;
    }
}

// ---------------- GEMM: 128x128 tile, BK=32, 4-deep tile ring, counted vmcnt ----------------
// Stage tile t+3 while computing tile t; vmcnt(12) retires exactly tile t's
// 4 loads each iteration (never 0 in steady state); 3-iter peeled tail.
// LDS 64KB: 4 bufs x (A 8KB | B 8KB). Swizzle: 16B slot g ^ ((row>>1)&3)
// (2-way max = free); staging source pre-swizzled to match.
template<bool OUT_BF16>
__global__ __launch_bounds__(256) void k_gemm(const unsigned short* __restrict__ A,
                                              const unsigned short* __restrict__ BT,
                                              const float* __restrict__ bias,
                                              void* __restrict__ Cout,
                                              int N, int Kd) {
    __shared__ __align__(16) unsigned char smem[65536];
    const int tid = threadIdx.x;
    const int lane = tid & 63, w = tid >> 6;
    const int g = lane >> 4, c = lane & 15;
    int nwg = gridDim.x * gridDim.y;
    int bid = blockIdx.y * gridDim.x + blockIdx.x;
    int sw = (bid & 7) * (nwg >> 3) + (bid >> 3);
    int bx = sw % gridDim.x, by = sw / gridDim.x;
    const int m0 = by * 128, n0 = bx * 128;
    const int wm = (w >> 1) * 64, wn = (w & 1) * 64;
    f32x4 acc[4][4] = {};

    // staging pointers: thread covers row (j*64 + w*16 + (l>>2)), col8 = (l&3)^((l>>3)&3)
    const int srow = w * 16 + (lane >> 2);
    const int scol = ((lane & 3) ^ ((lane >> 3) & 3)) * 8;
    const unsigned short* pA0 = A  + (size_t)(m0 + srow) * Kd + scol;
    const unsigned short* pA1 = pA0 + (size_t)64 * Kd;
    const unsigned short* pB0 = BT + (size_t)(n0 + srow) * Kd + scol;
    const unsigned short* pB1 = pB0 + (size_t)64 * Kd;
    // read-side swizzled byte offsets (within chunk): row*64 + ((g^key)*16)
    const int kc = (c >> 1) & 3;
    const int aoff = (wm + c) * 64 + ((g ^ kc) * 16);
    const int boff = (wn + c) * 64 + ((g ^ kc) * 16);

#define STAGE(buf)                                                                   \
    {                                                                                \
        unsigned short* lb = (unsigned short*)(smem + (buf) * 16384) + w * 512;      \
        gl16(pA0, lb);                                                               \
        gl16(pA1, lb + 2048);                                                        \
        gl16(pB0, lb + 4096);                                                        \
        gl16(pB1, lb + 6144);                                                        \
        pA0 += 32; pA1 += 32; pB0 += 32; pB1 += 32;                                  \
    }

#define COMPUTE(buf)                                                                 \
    {                                                                                \
        const unsigned char* Ab = smem + (buf) * 16384;                              \
        const unsigned char* Bb = Ab + 8192;                                         \
        bf16x8 af[4], bfr[4];                                                        \
        _Pragma("unroll") for (int mf = 0; mf < 4; ++mf)                             \
            af[mf] = *(const bf16x8*)(Ab + mf * 1024 + aoff);                        \
        _Pragma("unroll") for (int nf = 0; nf < 4; ++nf)                             \
            bfr[nf] = *(const bf16x8*)(Bb + nf * 1024 + boff);                       \
        __builtin_amdgcn_s_setprio(1);                                               \
        _Pragma("unroll") for (int mf = 0; mf < 4; ++mf)                             \
            _Pragma("unroll") for (int nf = 0; nf < 4; ++nf)                         \
                acc[mf][nf] = __builtin_amdgcn_mfma_f32_16x16x32_bf16(               \
                    af[mf], bfr[nf], acc[mf][nf], 0, 0, 0);                          \
        __builtin_amdgcn_s_setprio(0);                                               \
    }

    const int nt = Kd >> 5;
    // prologue: tiles 0,1,2 -> bufs 0,1,2
    STAGE(0); STAGE(1); STAGE(2);

    for (int t = 0; t < nt - 3; ++t) {
        STAGE((t + 3) & 3);
        asm volatile("s_waitcnt vmcnt(12)" ::: "memory");
        __builtin_amdgcn_s_barrier();
        __builtin_amdgcn_sched_barrier(0);
        COMPUTE(t & 3);
        __builtin_amdgcn_sched_barrier(0);
        __builtin_amdgcn_s_barrier();
    }
    // peeled tail: tiles nt-3, nt-2, nt-1
    asm volatile("s_waitcnt vmcnt(8)" ::: "memory");
    __builtin_amdgcn_s_barrier();
    __builtin_amdgcn_sched_barrier(0);
    COMPUTE((nt - 3) & 3);
    __builtin_amdgcn_sched_barrier(0);
    __builtin_amdgcn_s_barrier();
    asm volatile("s_waitcnt vmcnt(4)" ::: "memory");
    __builtin_amdgcn_s_barrier();
    __builtin_amdgcn_sched_barrier(0);
    COMPUTE((nt - 2) & 3);
    __builtin_amdgcn_sched_barrier(0);
    __builtin_amdgcn_s_barrier();
    asm volatile("s_waitcnt vmcnt(0)" ::: "memory");
    __builtin_amdgcn_s_barrier();
    __builtin_amdgcn_sched_barrier(0);
    COMPUTE((nt - 1) & 3);
#undef STAGE
#undef COMPUTE

#pragma unroll
    for (int mf = 0; mf < 4; ++mf)
#pragma unroll
        for (int nf = 0; nf < 4; ++nf) {
            int col = n0 + wn + nf * 16 + c;
            float bb = bias[col];
#pragma unroll
            for (int r = 0; r < 4; ++r) {
                int row = m0 + wm + mf * 16 + 4 * g + r;
                float v = acc[mf][nf][r] + bb;
                if (OUT_BF16)
                    ((unsigned short*)Cout)[(size_t)row * N + col] = f2bf(v);
                else
                    ((float*)Cout)[(size_t)row * N + col] = v;
            }
        }
}

// ---------------- repack K,V into MFMA-fragment order (producer-side gather) ----------------
//  K frag f: lane(l31,hi) -> K[tile*64 + (f>>2)*32 + l31][(f&3)*16 + hi*8 ..+8)
//  V frag f: lane(l31,hi) -> VT[(f&1)*32 + l31][tile*64 + (f>>2)*32 + ((f>>1)&1)*16 + hi*8 ..+8)
__global__ __launch_bounds__(256) void k_repack(const unsigned short* __restrict__ qkv,
                                                unsigned short* __restrict__ kfrag,
                                                unsigned short* __restrict__ vfrag) {
    int blk = blockIdx.x;
    int kt = blk & 31, h = (blk >> 5) & 15, b = blk >> 9;
    __shared__ unsigned short ktile[64][72];
    __shared__ unsigned short vtile[64][72];
    int tid = threadIdx.x;
#pragma unroll
    for (int j = 0; j < 2; ++j) {
        int cid = tid + j * 256;
        int row = cid >> 3, ch = (cid & 7) * 8;
        const unsigned short* base = qkv + (size_t)(b * SEQ + kt * 64 + row) * NCAT + h * 192;
        *(u16x8*)&ktile[row][ch] = *(const u16x8*)(base + 64 + ch);
        *(u16x8*)&vtile[row][ch] = *(const u16x8*)(base + 128 + ch);
    }
    __syncthreads();
    size_t obase = (size_t)blk * 4096;    // 4096 shorts = 8KB per (b,h,tile)
#pragma unroll
    for (int j = 0; j < 2; ++j) {
        int p = tid + j * 256;            // (frag,lane) pair: f = p>>6, lane = p&63
        int f = p >> 6, l31 = p & 31, hi = (p >> 5) & 1;
        *(u16x8*)(kfrag + obase + p * 8) =
            *(const u16x8*)&ktile[(f >> 2) * 32 + l31][(f & 3) * 16 + hi * 8];
        int vv = (f & 1) * 32 + l31;
        int k0 = (f >> 2) * 32 + ((f >> 1) & 1) * 16 + hi * 8;
        u16x8 o;
#pragma unroll
        for (int e = 0; e < 8; ++e) o[e] = vtile[k0 + e][vv];
        *(u16x8*)(vfrag + obase + p * 8) = o;
    }
}

// ---------------- flash attention: 32x32 MFMA, fragment LDS, coalesced staging ----------------
// (r8-proven version: 1024 blocks, NT=32, direct bf16 output)
__global__ __launch_bounds__(256) void k_attn(const unsigned short* __restrict__ qkv,
                                              const unsigned short* __restrict__ kfrag,
                                              const unsigned short* __restrict__ vfrag,
                                              unsigned short* __restrict__ attn) {
    int bid = blockIdx.x;
    int blk = (bid & 7) * 128 + (bid >> 3);   // XCD-chunked: 4 heads per XCD
    int qt = blk & 31, h = (blk >> 5) & 15, b = blk >> 9;
    int tid = threadIdx.x, w = tid >> 6, lane = tid & 63;
    int l31 = lane & 31, hi = lane >> 5;
    int qh = w & 1, kh = w >> 1;

    __shared__ __align__(16) unsigned char KV[2][16384];  // per buf: K frags 8KB | V frags 8KB

    const int qbase = b * SEQ + qt * 64;
    const unsigned short* qrow = qkv + (size_t)(qbase + qh * 32 + l31) * NCAT + h * 192;
    bf16x8 qf[4];
#pragma unroll
    for (int s = 0; s < 4; ++s) qf[s] = *(const bf16x8*)(qrow + s * 16 + hi * 8);

    f32x16 o0 = {}, o1 = {};
    float rsum = 0.f;

    const size_t fb = (size_t)(b * 512 + h * 32) * 4096;
    const unsigned short* ks0 = kfrag + fb + (w)     * 512 + lane * 8;
    const unsigned short* ks1 = kfrag + fb + (w + 4) * 512 + lane * 8;
    const unsigned short* vs0 = vfrag + fb + (w)     * 512 + lane * 8;
    const unsigned short* vs1 = vfrag + fb + (w + 4) * 512 + lane * 8;
    const unsigned kd0 = w * 1024, kd1 = (w + 4) * 1024;
    const unsigned vd0 = 8192 + w * 1024, vd1 = 8192 + (w + 4) * 1024;
    const int lx = lane * 16;

    gl16(ks0, (unsigned short*)&KV[0][kd0]);
    gl16(vs0, (unsigned short*)&KV[0][vd0]);
    gl16(ks1, (unsigned short*)&KV[0][kd1]);
    gl16(vs1, (unsigned short*)&KV[0][vd1]);
    ks0 += 4096; ks1 += 4096; vs0 += 4096; vs1 += 4096;
    asm volatile("s_waitcnt vmcnt(0)" ::: "memory");
    __builtin_amdgcn_s_barrier();

    const int NT = SEQ / 64;
    for (int t = 0; t < NT; ++t) {
        const int cur = t & 1;
        if (t + 1 < NT) {
            gl16(ks0, (unsigned short*)&KV[cur ^ 1][kd0]);
            gl16(vs0, (unsigned short*)&KV[cur ^ 1][vd0]);
            gl16(ks1, (unsigned short*)&KV[cur ^ 1][kd1]);
            gl16(vs1, (unsigned short*)&KV[cur ^ 1][vd1]);
            ks0 += 4096; ks1 += 4096; vs0 += 4096; vs1 += 4096;
            asm volatile("s_waitcnt vmcnt(4)" ::: "memory");
        } else {
            asm volatile("s_waitcnt vmcnt(0)" ::: "memory");
        }
        __builtin_amdgcn_s_barrier();
        __builtin_amdgcn_sched_barrier(0);

        const unsigned char* Kf = &KV[cur][0];
        const unsigned char* Vf = &KV[cur][8192];

        f32x16 st = {};
        __builtin_amdgcn_s_setprio(1);
#pragma unroll
        for (int s = 0; s < 4; ++s) {
            bf16x8 kf = *(const bf16x8*)(Kf + (kh * 4 + s) * 1024 + lx);
            st = __builtin_amdgcn_mfma_f32_32x32x16_bf16(kf, qf[s], st, 0, 0, 0);
        }
        __builtin_amdgcn_s_setprio(0);

#pragma unroll
        for (int r = 0; r < 16; ++r) {
            float p = __builtin_amdgcn_exp2f(st[r]);
            st[r] = p;
            rsum += p;
        }
        unsigned int d0, d1, d2, d3, d4, d5, d6, d7;
        asm("v_cvt_pk_bf16_f32 %0, %1, %2" : "=v"(d0) : "v"(st[0]),  "v"(st[1]));
        asm("v_cvt_pk_bf16_f32 %0, %1, %2" : "=v"(d1) : "v"(st[2]),  "v"(st[3]));
        asm("v_cvt_pk_bf16_f32 %0, %1, %2" : "=v"(d2) : "v"(st[4]),  "v"(st[5]));
        asm("v_cvt_pk_bf16_f32 %0, %1, %2" : "=v"(d3) : "v"(st[6]),  "v"(st[7]));
        asm("v_cvt_pk_bf16_f32 %0, %1, %2" : "=v"(d4) : "v"(st[8]),  "v"(st[9]));
        asm("v_cvt_pk_bf16_f32 %0, %1, %2" : "=v"(d5) : "v"(st[10]), "v"(st[11]));
        asm("v_cvt_pk_bf16_f32 %0, %1, %2" : "=v"(d6) : "v"(st[12]), "v"(st[13]));
        asm("v_cvt_pk_bf16_f32 %0, %1, %2" : "=v"(d7) : "v"(st[14]), "v"(st[15]));
        asm("v_permlane32_swap_b32 %0, %1" : "+v"(d0), "+v"(d2));
        asm("v_permlane32_swap_b32 %0, %1" : "+v"(d1), "+v"(d3));
        asm("v_permlane32_swap_b32 %0, %1" : "+v"(d4), "+v"(d6));
        asm("v_permlane32_swap_b32 %0, %1" : "+v"(d5), "+v"(d7));
        union { unsigned int u[4]; bf16x8 v; } pa0, pa1;
        pa0.u[0] = d0; pa0.u[1] = d1; pa0.u[2] = d2; pa0.u[3] = d3;
        pa1.u[0] = d4; pa1.u[1] = d5; pa1.u[2] = d6; pa1.u[3] = d7;

        __builtin_amdgcn_s_setprio(1);
        {
            bf16x8 vf00 = *(const bf16x8*)(Vf + (kh * 4 + 0) * 1024 + lx);
            bf16x8 vf01 = *(const bf16x8*)(Vf + (kh * 4 + 1) * 1024 + lx);
            bf16x8 vf10 = *(const bf16x8*)(Vf + (kh * 4 + 2) * 1024 + lx);
            bf16x8 vf11 = *(const bf16x8*)(Vf + (kh * 4 + 3) * 1024 + lx);
            o0 = __builtin_amdgcn_mfma_f32_32x32x16_bf16(pa0.v, vf00, o0, 0, 0, 0);
            o1 = __builtin_amdgcn_mfma_f32_32x32x16_bf16(pa0.v, vf01, o1, 0, 0, 0);
            o0 = __builtin_amdgcn_mfma_f32_32x32x16_bf16(pa1.v, vf10, o0, 0, 0, 0);
            o1 = __builtin_amdgcn_mfma_f32_32x32x16_bf16(pa1.v, vf11, o1, 0, 0, 0);
        }
        __builtin_amdgcn_s_setprio(0);
        __builtin_amdgcn_sched_barrier(0);
        __builtin_amdgcn_s_barrier();
    }

    rsum += __shfl_xor(rsum, 32);
    __syncthreads();
    float* red = (float*)&KV[0][0];          // [2 qh][32 q][64 v] f32 = 16 KB
    float* rsb = (float*)&KV[1][0];          // [2 kh][2 qh][32 q] f32
    if (kh == 1) {
#pragma unroll
        for (int r = 0; r < 16; ++r) {
            int q = (r & 3) + 8 * (r >> 2) + 4 * hi;
            red[(qh * 32 + q) * 64 + l31]      = o0[r];
            red[(qh * 32 + q) * 64 + 32 + l31] = o1[r];
        }
    }
    if (lane < 32) rsb[(kh * 2 + qh) * 32 + l31] = rsum;
    __syncthreads();
    if (kh == 0) {
#pragma unroll
        for (int r = 0; r < 16; ++r) {
            int q = (r & 3) + 8 * (r >> 2) + 4 * hi;
            float tot = rsb[qh * 32 + q] + rsb[(2 + qh) * 32 + q];
            float inv = 1.0f / tot;
            float v0 = (o0[r] + red[(qh * 32 + q) * 64 + l31]) * inv;
            float v1 = (o1[r] + red[(qh * 32 + q) * 64 + 32 + l31]) * inv;
            int row = qbase + qh * 32 + q;
            attn[(size_t)row * (HEADS * QDIM) + h * QDIM + l31]      = f2bf(v0);
            attn[(size_t)row * (HEADS * QDIM) + h * QDIM + 32 + l31] = f2bf(v1);
        }
    }
}

extern "C" void kernel_launch(void* const* d_in, const int* in_sizes, int n_in,
                              void* d_out, int out_size, void* d_ws, size_t ws_size,
                              hipStream_t stream) {
    const float* xi = (const float*)d_in[0];
    const float* Wq = (const float*)d_in[1];
    const float* bq = (const float*)d_in[2];
    const float* Wk = (const float*)d_in[3];
    const float* bk = (const float*)d_in[4];
    const float* Wv = (const float*)d_in[5];
    const float* bv = (const float*)d_in[6];
    const float* Wo = (const float*)d_in[7];
    const float* bo = (const float*)d_in[8];

    unsigned short* xi_bf = (unsigned short*)d_ws;
    unsigned short* WcatT = xi_bf + (size_t)M_ROWS * D_MODEL;
    unsigned short* WoT   = WcatT + (size_t)NCAT * D_MODEL;
    float*          bcat  = (float*)(WoT + (size_t)D_MODEL * D_MODEL);
    unsigned short* qkvc  = (unsigned short*)(bcat + NCAT);
    unsigned short* kfrag = qkvc + (size_t)M_ROWS * NCAT;
    unsigned short* vfrag = kfrag + (size_t)BATCH * HEADS * 32 * 4096;
    unsigned short* attnb = vfrag + (size_t)BATCH * HEADS * 32 * 4096;

    // fold softmax scale AND log2(e) into Q projection (attn uses exp2)
    float qscale = 1.4426950408889634f / sqrtf((float)SEQ);

    k_cvt_bf16<<<(M_ROWS * D_MODEL) / 2048, 256, 0, stream>>>(xi, xi_bf);
    k_prep_wcat<<<768, 256, 0, stream>>>(Wq, Wk, Wv, bq, bk, bv, WcatT, bcat, qscale);
    k_prep_wo<<<256, 256, 0, stream>>>(Wo, WoT);

    k_gemm<true><<<dim3(NCAT / 128, M_ROWS / 128), 256, 0, stream>>>(
        xi_bf, WcatT, bcat, (void*)qkvc, NCAT, D_MODEL);

    k_repack<<<BATCH * HEADS * (SEQ / 64), 256, 0, stream>>>(qkvc, kfrag, vfrag);

    k_attn<<<BATCH * HEADS * (SEQ / 64), 256, 0, stream>>>(qkvc, kfrag, vfrag, attnb);

    k_gemm<false><<<dim3(D_MODEL / 128, M_ROWS / 128), 256, 0, stream>>>(
        attnb, WoT, bo, d_out, D_MODEL, D_MODEL);
}

// Round 11
// 119.553 us; speedup vs baseline: 1.1315x; 1.0628x over previous
//
#include <hip/hip_runtime.h>
#include <math.h>

typedef __bf16 bf16x8 __attribute__((ext_vector_type(8)));
typedef float  f32x4  __attribute__((ext_vector_type(4)));
typedef float  f32x16 __attribute__((ext_vector_type(16)));
typedef unsigned short u16x8 __attribute__((ext_vector_type(8)));

#define D_MODEL 1024
#define QDIM    64
#define HEADS   16
#define BATCH   2
#define SEQ     2048
#define M_ROWS  (BATCH*SEQ)        /* 4096 */
#define NCAT    (HEADS*3*QDIM)     /* 3072 */

__device__ __forceinline__ unsigned short f2bf(float f) {
    unsigned int u = __float_as_uint(f);
    u += 0x7fffu + ((u >> 16) & 1u);
    return (unsigned short)(u >> 16);
}

// async global->LDS, 16B per lane. LDS dest = wave-uniform base + lane*16.
__device__ __forceinline__ void gl16(const unsigned short* g, unsigned short* l) {
    __builtin_amdgcn_global_load_lds(
        (const __attribute__((address_space(1))) unsigned int*)g,
        (__attribute__((address_space(3))) unsigned int*)l, 16, 0, 0);
}

// ---------------- cast xi f32 -> bf16 ----------------
__global__ __launch_bounds__(256) void k_cvt_bf16(const float* __restrict__ in,
                                                  unsigned short* __restrict__ out) {
    int i = (blockIdx.x * 256 + threadIdx.x) * 8;
    f32x4 a = *(const f32x4*)(in + i);
    f32x4 b = *(const f32x4*)(in + i + 4);
    u16x8 o;
    o[0]=f2bf(a[0]); o[1]=f2bf(a[1]); o[2]=f2bf(a[2]); o[3]=f2bf(a[3]);
    o[4]=f2bf(b[0]); o[5]=f2bf(b[1]); o[6]=f2bf(b[2]); o[7]=f2bf(b[3]);
    *(u16x8*)(out + i) = o;
}

// ------- merged weight prep: blocks 0..767 build WcatT+bcat, 768..1023 build WoT -------
// Q weights pre-scaled by log2(e)/sqrt(SEQ) so attn can use exp2 directly.
__global__ __launch_bounds__(256) void k_prep_w(const float* __restrict__ Wq,
                                                const float* __restrict__ Wk,
                                                const float* __restrict__ Wv,
                                                const float* __restrict__ bq,
                                                const float* __restrict__ bk,
                                                const float* __restrict__ bv,
                                                const float* __restrict__ Wo,
                                                unsigned short* __restrict__ WcatT,
                                                float* __restrict__ bcat,
                                                unsigned short* __restrict__ WoT,
                                                float qscale) {
    __shared__ float t[64][65];
    int tid = threadIdx.x;
    int dr = tid >> 2, qc = (tid & 3) * 16;
    if (blockIdx.x < 768) {
        int blk = blockIdx.x;
        int dt = blk & 15, h = (blk >> 4) & 15, s = blk >> 8;
        const float* W = (s == 0) ? Wq : (s == 1) ? Wk : Wv;
        float sc = (s == 0) ? qscale : 1.0f;
        const float* src = W + (size_t)h * (D_MODEL * QDIM) + (size_t)(dt * 64 + dr) * QDIM + qc;
#pragma unroll
        for (int j = 0; j < 4; ++j) {
            f32x4 v = *(const f32x4*)(src + j * 4);
            t[dr][qc + j * 4 + 0] = v[0]; t[dr][qc + j * 4 + 1] = v[1];
            t[dr][qc + j * 4 + 2] = v[2]; t[dr][qc + j * 4 + 3] = v[3];
        }
        __syncthreads();
        int q = tid >> 2, dc = (tid & 3) * 16;
        unsigned short* dst = WcatT + (size_t)(h * 192 + s * 64 + q) * D_MODEL + dt * 64 + dc;
#pragma unroll
        for (int j = 0; j < 2; ++j) {
            u16x8 o;
#pragma unroll
            for (int e = 0; e < 8; ++e) o[e] = f2bf(t[dc + j * 8 + e][q] * sc);
            *(u16x8*)(dst + j * 8) = o;
        }
        if (dt == 0 && tid < 64) {
            const float* bb = (s == 0) ? bq : (s == 1) ? bk : bv;
            bcat[h * 192 + s * 64 + tid] = bb[h * QDIM + tid] * sc;
        }
    } else {
        int blk = blockIdx.x - 768;
        int ct = blk & 15, rt = blk >> 4;
        const float* src = Wo + (size_t)(rt * 64 + dr) * D_MODEL + ct * 64 + qc;
#pragma unroll
        for (int j = 0; j < 4; ++j) {
            f32x4 v = *(const f32x4*)(src + j * 4);
            t[dr][qc + j * 4 + 0] = v[0]; t[dr][qc + j * 4 + 1] = v[1];
            t[dr][qc + j * 4 + 2] = v[2]; t[dr][qc + j * 4 + 3] = v[3];
        }
        __syncthreads();
        int q = tid >> 2, dc = (tid & 3) * 16;
        unsigned short* dst = WoT + (size_t)(ct * 64 + q) * D_MODEL + rt * 64 + dc;
#pragma unroll
        for (int j = 0; j < 2; ++j) {
            u16x8 o;
#pragma unroll
            for (int e = 0; e < 8; ++e) o[e] = f2bf(t[dc + j * 8 + e][q]);
            *(u16x8*)(dst + j * 8) = o;
        }
    }
}

// ---------------- GEMM: 128x128 tile, BK=32, 4-deep tile ring, counted vmcnt ----------------
template<bool OUT_BF16>
__global__ __launch_bounds__(256) void k_gemm(const unsigned short* __restrict__ A,
                                              const unsigned short* __restrict__ BT,
                                              const float* __restrict__ bias,
                                              void* __restrict__ Cout,
                                              int N, int Kd) {
    __shared__ __align__(16) unsigned char smem[65536];
    const int tid = threadIdx.x;
    const int lane = tid & 63, w = tid >> 6;
    const int g = lane >> 4, c = lane & 15;
    int nwg = gridDim.x * gridDim.y;
    int bid = blockIdx.y * gridDim.x + blockIdx.x;
    int sw = (bid & 7) * (nwg >> 3) + (bid >> 3);
    int bx = sw % gridDim.x, by = sw / gridDim.x;
    const int m0 = by * 128, n0 = bx * 128;
    const int wm = (w >> 1) * 64, wn = (w & 1) * 64;
    f32x4 acc[4][4] = {};

    const int srow = w * 16 + (lane >> 2);
    const int scol = ((lane & 3) ^ ((lane >> 3) & 3)) * 8;
    const unsigned short* pA0 = A  + (size_t)(m0 + srow) * Kd + scol;
    const unsigned short* pA1 = pA0 + (size_t)64 * Kd;
    const unsigned short* pB0 = BT + (size_t)(n0 + srow) * Kd + scol;
    const unsigned short* pB1 = pB0 + (size_t)64 * Kd;
    const int kc = (c >> 1) & 3;
    const int aoff = (wm + c) * 64 + ((g ^ kc) * 16);
    const int boff = (wn + c) * 64 + ((g ^ kc) * 16);

#define STAGE(buf)                                                                   \
    {                                                                                \
        unsigned short* lb = (unsigned short*)(smem + (buf) * 16384) + w * 512;      \
        gl16(pA0, lb);                                                               \
        gl16(pA1, lb + 2048);                                                        \
        gl16(pB0, lb + 4096);                                                        \
        gl16(pB1, lb + 6144);                                                        \
        pA0 += 32; pA1 += 32; pB0 += 32; pB1 += 32;                                  \
    }

#define COMPUTE(buf)                                                                 \
    {                                                                                \
        const unsigned char* Ab = smem + (buf) * 16384;                              \
        const unsigned char* Bb = Ab + 8192;                                         \
        bf16x8 af[4], bfr[4];                                                        \
        _Pragma("unroll") for (int mf = 0; mf < 4; ++mf)                             \
            af[mf] = *(const bf16x8*)(Ab + mf * 1024 + aoff);                        \
        _Pragma("unroll") for (int nf = 0; nf < 4; ++nf)                             \
            bfr[nf] = *(const bf16x8*)(Bb + nf * 1024 + boff);                       \
        __builtin_amdgcn_s_setprio(1);                                               \
        _Pragma("unroll") for (int mf = 0; mf < 4; ++mf)                             \
            _Pragma("unroll") for (int nf = 0; nf < 4; ++nf)                         \
                acc[mf][nf] = __builtin_amdgcn_mfma_f32_16x16x32_bf16(               \
                    af[mf], bfr[nf], acc[mf][nf], 0, 0, 0);                          \
        __builtin_amdgcn_s_setprio(0);                                               \
    }

    const int nt = Kd >> 5;
    STAGE(0); STAGE(1); STAGE(2);

    for (int t = 0; t < nt - 3; ++t) {
        STAGE((t + 3) & 3);
        asm volatile("s_waitcnt vmcnt(12)" ::: "memory");
        __builtin_amdgcn_s_barrier();
        __builtin_amdgcn_sched_barrier(0);
        COMPUTE(t & 3);
        __builtin_amdgcn_sched_barrier(0);
        __builtin_amdgcn_s_barrier();
    }
    asm volatile("s_waitcnt vmcnt(8)" ::: "memory");
    __builtin_amdgcn_s_barrier();
    __builtin_amdgcn_sched_barrier(0);
    COMPUTE((nt - 3) & 3);
    __builtin_amdgcn_sched_barrier(0);
    __builtin_amdgcn_s_barrier();
    asm volatile("s_waitcnt vmcnt(4)" ::: "memory");
    __builtin_amdgcn_s_barrier();
    __builtin_amdgcn_sched_barrier(0);
    COMPUTE((nt - 2) & 3);
    __builtin_amdgcn_sched_barrier(0);
    __builtin_amdgcn_s_barrier();
    asm volatile("s_waitcnt vmcnt(0)" ::: "memory");
    __builtin_amdgcn_s_barrier();
    __builtin_amdgcn_sched_barrier(0);
    COMPUTE((nt - 1) & 3);
#undef STAGE
#undef COMPUTE

#pragma unroll
    for (int mf = 0; mf < 4; ++mf)
#pragma unroll
        for (int nf = 0; nf < 4; ++nf) {
            int col = n0 + wn + nf * 16 + c;
            float bb = bias[col];
#pragma unroll
            for (int r = 0; r < 4; ++r) {
                int row = m0 + wm + mf * 16 + 4 * g + r;
                float v = acc[mf][nf][r] + bb;
                if (OUT_BF16)
                    ((unsigned short*)Cout)[(size_t)row * N + col] = f2bf(v);
                else
                    ((float*)Cout)[(size_t)row * N + col] = v;
            }
        }
}

// ---------------- repack K,V into MFMA-fragment order (producer-side gather) ----------------
//  K frag f: lane(l31,hi) -> K[tile*64 + (f>>2)*32 + l31][(f&3)*16 + hi*8 ..+8)
//  V frag f: lane(l31,hi) -> VT[(f&1)*32 + l31][tile*64 + (f>>2)*32 + ((f>>1)&1)*16 + hi*8 ..+8)
__global__ __launch_bounds__(256) void k_repack(const unsigned short* __restrict__ qkv,
                                                unsigned short* __restrict__ kfrag,
                                                unsigned short* __restrict__ vfrag) {
    int blk = blockIdx.x;
    int kt = blk & 31, h = (blk >> 5) & 15, b = blk >> 9;
    __shared__ unsigned short ktile[64][72];
    __shared__ unsigned short vtile[64][72];
    int tid = threadIdx.x;
#pragma unroll
    for (int j = 0; j < 2; ++j) {
        int cid = tid + j * 256;
        int row = cid >> 3, ch = (cid & 7) * 8;
        const unsigned short* base = qkv + (size_t)(b * SEQ + kt * 64 + row) * NCAT + h * 192;
        *(u16x8*)&ktile[row][ch] = *(const u16x8*)(base + 64 + ch);
        *(u16x8*)&vtile[row][ch] = *(const u16x8*)(base + 128 + ch);
    }
    __syncthreads();
    size_t obase = (size_t)blk * 4096;
#pragma unroll
    for (int j = 0; j < 2; ++j) {
        int p = tid + j * 256;
        int f = p >> 6, l31 = p & 31, hi = (p >> 5) & 1;
        *(u16x8*)(kfrag + obase + p * 8) =
            *(const u16x8*)&ktile[(f >> 2) * 32 + l31][(f & 3) * 16 + hi * 8];
        int vv = (f & 1) * 32 + l31;
        int k0 = (f >> 2) * 32 + ((f >> 1) & 1) * 16 + hi * 8;
        u16x8 o;
#pragma unroll
        for (int e = 0; e < 8; ++e) o[e] = vtile[k0 + e][vv];
        *(u16x8*)(vfrag + obase + p * 8) = o;
    }
}

// ---------------- flash attention: barrier-free, register-pipelined ----------------
// block = (b,h,64 q); 4 waves: qh = w&1, kh = w>>1 — fully independent in the
// main loop. Each wave loads its 8 fragments per tile global->VGPR (1KB
// coalesced per load, L2-resident), 2-tile register pipeline with named A/B
// sets (no LDS, no per-tile barriers). LDS only for the kh-merge epilogue.
__global__ __launch_bounds__(256) void k_attn(const unsigned short* __restrict__ qkv,
                                              const unsigned short* __restrict__ kfrag,
                                              const unsigned short* __restrict__ vfrag,
                                              unsigned short* __restrict__ attn) {
    int bid = blockIdx.x;
    int blk = (bid & 7) * 128 + (bid >> 3);   // XCD-chunked: 4 heads per XCD
    int qt = blk & 31, h = (blk >> 5) & 15, b = blk >> 9;
    int tid = threadIdx.x, w = tid >> 6, lane = tid & 63;
    int l31 = lane & 31, hi = lane >> 5;
    int qh = w & 1, kh = w >> 1;

    __shared__ float red[4096];   // [64 q][64 v] f32 = 16 KB (epilogue only)
    __shared__ float rsb[128];    // [2 kh][2 qh][32 q]

    const int qbase = b * SEQ + qt * 64;
    const unsigned short* qrow = qkv + (size_t)(qbase + qh * 32 + l31) * NCAT + h * 192;
    bf16x8 qf0 = *(const bf16x8*)(qrow + 0 * 16 + hi * 8);
    bf16x8 qf1 = *(const bf16x8*)(qrow + 1 * 16 + hi * 8);
    bf16x8 qf2 = *(const bf16x8*)(qrow + 2 * 16 + hi * 8);
    bf16x8 qf3 = *(const bf16x8*)(qrow + 3 * 16 + hi * 8);

    f32x16 o0 = {}, o1 = {};
    float rsum = 0.f;

    // per-wave fragment streams (fragment order; tiles advance by 4096 shorts)
    const size_t fb = (size_t)(b * 512 + h * 32) * 4096 + (size_t)(kh * 4) * 512 + lane * 8;
    const unsigned short* kp = kfrag + fb;
    const unsigned short* vp = vfrag + fb;

    bf16x8 aK0, aK1, aK2, aK3, aV0, aV1, aV2, aV3;
    bf16x8 bK0, bK1, bK2, bK3, bV0, bV1, bV2, bV3;

#define LOADT(K0, K1, K2, K3, V0, V1, V2, V3)                   \
    {                                                           \
        K0 = *(const bf16x8*)(kp);                              \
        K1 = *(const bf16x8*)(kp + 512);                        \
        K2 = *(const bf16x8*)(kp + 1024);                       \
        K3 = *(const bf16x8*)(kp + 1536);                       \
        V0 = *(const bf16x8*)(vp);                              \
        V1 = *(const bf16x8*)(vp + 512);                        \
        V2 = *(const bf16x8*)(vp + 1024);                       \
        V3 = *(const bf16x8*)(vp + 1536);                       \
        kp += 4096; vp += 4096;                                 \
    }

#define COMPUTE(K0, K1, K2, K3, V0, V1, V2, V3)                                       \
    {                                                                                 \
        f32x16 st = {};                                                               \
        st = __builtin_amdgcn_mfma_f32_32x32x16_bf16(K0, qf0, st, 0, 0, 0);           \
        st = __builtin_amdgcn_mfma_f32_32x32x16_bf16(K1, qf1, st, 0, 0, 0);           \
        st = __builtin_amdgcn_mfma_f32_32x32x16_bf16(K2, qf2, st, 0, 0, 0);           \
        st = __builtin_amdgcn_mfma_f32_32x32x16_bf16(K3, qf3, st, 0, 0, 0);           \
        _Pragma("unroll") for (int r = 0; r < 16; ++r) {                              \
            float p = __builtin_amdgcn_exp2f(st[r]);                                  \
            st[r] = p;                                                                \
            rsum += p;                                                                \
        }                                                                             \
        unsigned int d0, d1, d2, d3, d4, d5, d6, d7;                                  \
        asm("v_cvt_pk_bf16_f32 %0, %1, %2" : "=v"(d0) : "v"(st[0]),  "v"(st[1]));     \
        asm("v_cvt_pk_bf16_f32 %0, %1, %2" : "=v"(d1) : "v"(st[2]),  "v"(st[3]));     \
        asm("v_cvt_pk_bf16_f32 %0, %1, %2" : "=v"(d2) : "v"(st[4]),  "v"(st[5]));     \
        asm("v_cvt_pk_bf16_f32 %0, %1, %2" : "=v"(d3) : "v"(st[6]),  "v"(st[7]));     \
        asm("v_cvt_pk_bf16_f32 %0, %1, %2" : "=v"(d4) : "v"(st[8]),  "v"(st[9]));     \
        asm("v_cvt_pk_bf16_f32 %0, %1, %2" : "=v"(d5) : "v"(st[10]), "v"(st[11]));    \
        asm("v_cvt_pk_bf16_f32 %0, %1, %2" : "=v"(d6) : "v"(st[12]), "v"(st[13]));    \
        asm("v_cvt_pk_bf16_f32 %0, %1, %2" : "=v"(d7) : "v"(st[14]), "v"(st[15]));    \
        asm("v_permlane32_swap_b32 %0, %1" : "+v"(d0), "+v"(d2));                     \
        asm("v_permlane32_swap_b32 %0, %1" : "+v"(d1), "+v"(d3));                     \
        asm("v_permlane32_swap_b32 %0, %1" : "+v"(d4), "+v"(d6));                     \
        asm("v_permlane32_swap_b32 %0, %1" : "+v"(d5), "+v"(d7));                     \
        union { unsigned int u[4]; bf16x8 v; } pa0, pa1;                              \
        pa0.u[0] = d0; pa0.u[1] = d1; pa0.u[2] = d2; pa0.u[3] = d3;                   \
        pa1.u[0] = d4; pa1.u[1] = d5; pa1.u[2] = d6; pa1.u[3] = d7;                   \
        o0 = __builtin_amdgcn_mfma_f32_32x32x16_bf16(pa0.v, V0, o0, 0, 0, 0);         \
        o1 = __builtin_amdgcn_mfma_f32_32x32x16_bf16(pa0.v, V1, o1, 0, 0, 0);         \
        o0 = __builtin_amdgcn_mfma_f32_32x32x16_bf16(pa1.v, V2, o0, 0, 0, 0);         \
        o1 = __builtin_amdgcn_mfma_f32_32x32x16_bf16(pa1.v, V3, o1, 0, 0, 0);         \
    }

    // prologue: tile 0 -> set A
    LOADT(aK0, aK1, aK2, aK3, aV0, aV1, aV2, aV3);

    const int NT = SEQ / 64;   // 32, even
    for (int t = 0; t < NT; t += 2) {
        LOADT(bK0, bK1, bK2, bK3, bV0, bV1, bV2, bV3);          // tile t+1
        COMPUTE(aK0, aK1, aK2, aK3, aV0, aV1, aV2, aV3);        // tile t
        if (t + 2 < NT)
            LOADT(aK0, aK1, aK2, aK3, aV0, aV1, aV2, aV3);      // tile t+2
        COMPUTE(bK0, bK1, bK2, bK3, bV0, bV1, bV2, bV3);        // tile t+1
    }
#undef LOADT
#undef COMPUTE

    // ---- merge kh partials + normalize + store ----
    rsum += __shfl_xor(rsum, 32);
    if (kh == 1) {
#pragma unroll
        for (int r = 0; r < 16; ++r) {
            int q = (r & 3) + 8 * (r >> 2) + 4 * hi;
            red[(qh * 32 + q) * 64 + l31]      = o0[r];
            red[(qh * 32 + q) * 64 + 32 + l31] = o1[r];
        }
    }
    if (lane < 32) rsb[(kh * 2 + qh) * 32 + l31] = rsum;
    __syncthreads();
    if (kh == 0) {
#pragma unroll
        for (int r = 0; r < 16; ++r) {
            int q = (r & 3) + 8 * (r >> 2) + 4 * hi;
            float tot = rsb[qh * 32 + q] + rsb[(2 + qh) * 32 + q];
            float inv = 1.0f / tot;
            float v0 = (o0[r] + red[(qh * 32 + q) * 64 + l31]) * inv;
            float v1 = (o1[r] + red[(qh * 32 + q) * 64 + 32 + l31]) * inv;
            int row = qbase + qh * 32 + q;
            attn[(size_t)row * (HEADS * QDIM) + h * QDIM + l31]      = f2bf(v0);
            attn[(size_t)row * (HEADS * QDIM) + h * QDIM + 32 + l31] = f2bf(v1);
        }
    }
}

extern "C" void kernel_launch(void* const* d_in, const int* in_sizes, int n_in,
                              void* d_out, int out_size, void* d_ws, size_t ws_size,
                              hipStream_t stream) {
    const float* xi = (const float*)d_in[0];
    const float* Wq = (const float*)d_in[1];
    const float* bq = (const float*)d_in[2];
    const float* Wk = (const float*)d_in[3];
    const float* bk = (const float*)d_in[4];
    const float* Wv = (const float*)d_in[5];
    const float* bv = (const float*)d_in[6];
    const float* Wo = (const float*)d_in[7];
    const float* bo = (const float*)d_in[8];

    unsigned short* xi_bf = (unsigned short*)d_ws;
    unsigned short* WcatT = xi_bf + (size_t)M_ROWS * D_MODEL;
    unsigned short* WoT   = WcatT + (size_t)NCAT * D_MODEL;
    float*          bcat  = (float*)(WoT + (size_t)D_MODEL * D_MODEL);
    unsigned short* qkvc  = (unsigned short*)(bcat + NCAT);
    unsigned short* kfrag = qkvc + (size_t)M_ROWS * NCAT;
    unsigned short* vfrag = kfrag + (size_t)BATCH * HEADS * 32 * 4096;
    unsigned short* attnb = vfrag + (size_t)BATCH * HEADS * 32 * 4096;

    // fold softmax scale AND log2(e) into Q projection (attn uses exp2)
    float qscale = 1.4426950408889634f / sqrtf((float)SEQ);

    k_cvt_bf16<<<(M_ROWS * D_MODEL) / 2048, 256, 0, stream>>>(xi, xi_bf);
    k_prep_w<<<1024, 256, 0, stream>>>(Wq, Wk, Wv, bq, bk, bv, Wo, WcatT, bcat, WoT, qscale);

    k_gemm<true><<<dim3(NCAT / 128, M_ROWS / 128), 256, 0, stream>>>(
        xi_bf, WcatT, bcat, (void*)qkvc, NCAT, D_MODEL);

    k_repack<<<BATCH * HEADS * (SEQ / 64), 256, 0, stream>>>(qkvc, kfrag, vfrag);

    k_attn<<<BATCH * HEADS * (SEQ / 64), 256, 0, stream>>>(qkvc, kfrag, vfrag, attnb);

    k_gemm<false><<<dim3(D_MODEL / 128, M_ROWS / 128), 256, 0, stream>>>(
        attnb, WoT, bo, d_out, D_MODEL, D_MODEL);
}